// Round 2
// baseline (254.757 us; speedup 1.0000x reference)
//
#include <hip/hip_runtime.h>
#include <stdint.h>
#include <math.h>

// Problem constants
constexpr int Kk  = 1024;

// d_out layout (floats)
constexpr int OUT0_N   = 32 * 64 * 1024;       // 2097152 (z_st, [B,D,H,W])
constexpr int OUT_LOSS = OUT0_N;               // 2097152
constexpr int OUT_PERP = OUT0_N + 1;           // 2097153
constexpr int OUT_ENC  = OUT0_N + 2;           // 2097154

// d_ws layout (bytes) — everything fully written each call (ws is poisoned):
//   [0     .. 4096)    counts u32[1024]     (zeroed by D block 0)
//   [4096  .. 8192)    loss partials double[512] (fully written by finish)
//   [8192  .. 12288)   Bn_g float[1024]     exact code norms (D block 0)
//   [12288 .. 143360)  rowinfo u32[32768]   cand codes+count (fully written by D)
constexpr size_t WS_CNT = 0;
constexpr size_t WS_LP  = 4096;
constexpr size_t WS_BN  = 8192;
constexpr size_t WS_RI  = 12288;

typedef short bf16x8 __attribute__((ext_vector_type(8)));
typedef float f32x16 __attribute__((ext_vector_type(16)));

// ---------------------------------------------------------------------------
// numpy-bit-exact 64-elem squared-norm: tt[d]=fl(x*x), 8 stride-8 sequential
// accumulators, pairwise combine. Contraction OFF. p: 16B-aligned, contiguous.
// ---------------------------------------------------------------------------
__device__ __forceinline__ float norm64v(const float4* __restrict__ p) {
#pragma clang fp contract(off)
    float tt[64];
#pragma unroll
    for (int q = 0; q < 16; ++q) {
        float4 v = p[q];
        tt[4 * q + 0] = v.x * v.x;
        tt[4 * q + 1] = v.y * v.y;
        tt[4 * q + 2] = v.z * v.z;
        tt[4 * q + 3] = v.w * v.w;
    }
    float r[8];
#pragma unroll
    for (int j = 0; j < 8; ++j) r[j] = tt[j];
#pragma unroll
    for (int i = 8; i < 64; i += 8)
#pragma unroll
        for (int j = 0; j < 8; ++j) r[j] += tt[i + j];
    return ((r[0] + r[1]) + (r[2] + r[3])) + ((r[4] + r[5]) + (r[6] + r[7]));
}

__device__ __forceinline__ uint32_t fsort(float f) {
    uint32_t b = __float_as_uint(f);
    return (b & 0x80000000u) ? ~b : (b | 0x80000000u);
}

// RNE float->bf16 (finite inputs only; data is well inside normal range)
__device__ __forceinline__ unsigned short f2bf(float f) {
    uint32_t u = __float_as_uint(f);
    uint32_t r = (u + 0x7fffu + ((u >> 16) & 1u)) >> 16;
    return (unsigned short)r;
}

// ---------------------------------------------------------------------------
// dist_mfma: 256 blocks x 256 thr, 1 block/CU (135 KB LDS).
// Replaces the exact-fp32 GEMM (R5: ~60us LDS/VALU-bound) with a bf16 MFMA
// screen + provable margin. Only the argmin INDEX feeds outputs, so distances
// need not be bit-exact — only the candidate set must provably contain the
// numpy argmin. Error bound (worst case, Cauchy-Schwarz over d):
//   |(D_k - A) - s_hat_k| <= 2^-8*1.01*2*||x||*maxE + 8.6e-6  =: eps
// margin = 2*eps (inflated: 0.017*||x||*maxE + 1e-4). Pass 1 finds the row
// min of s_hat; pass 2 collects all codes within margin (winner provably
// included; non-candidates provably strictly lose). Layout-permutation
// safety: A and B fragments are packed with the SAME (lane>>5, elem)->k map,
// so the MFMA dot product is correct for ANY hardware k-order (dot products
// are permutation-invariant; C/D layout is the m74/m101-verified one).
// The 134 MB enc zero-fill interleaves with the tiles — this kernel is
// store-drain-bound (~24us), all compute hidden under it.
// ---------------------------------------------------------------------------
__global__ __launch_bounds__(256, 1)
void dist_mfma(const float* __restrict__ z_e, const float* __restrict__ emb,
               uint32_t* __restrict__ rowinfo, uint32_t* __restrict__ counts,
               float* __restrict__ Bn_g, float* __restrict__ out) {
    __shared__ unsigned short ebf[1024 * 64];   // 128 KB bf16 codes, swizzled
    __shared__ float Bn_s[1024];
    __shared__ float wmax[4];
    const int t = threadIdx.x;
    const int lane = t & 63, wv = t >> 6;
    const int g = lane >> 5;                    // k-half within MFMA operand
    const int n0 = blockIdx.x * 128;
    const int b = n0 >> 10;
    const int hw = (n0 & 1023) + wv * 32 + (lane & 31);

    // ---- stage all 1024 codes as bf16 into LDS (XOR-swizzle 16B slots
    //      within each 128B row: byte ^= (code&7)<<4 — G4/T2 pattern) ----
    {
        const float4* e4 = (const float4*)emb;
#pragma unroll 8
        for (int it = 0; it < 64; ++it) {
            int j = t + it * 256;               // 0..16383
            float4 v = e4[j];
            int code = j >> 4, q = j & 15;
            ushort4 bv;
            bv.x = f2bf(v.x); bv.y = f2bf(v.y); bv.z = f2bf(v.z); bv.w = f2bf(v.w);
            int byte = code * 128 + ((q * 8) ^ ((code & 7) << 4));
            *(ushort4*)((char*)ebf + byte) = bv;
        }
    }

    // ---- exact code norms (numpy-bit-exact, shared with finish via Bn_g)
    //      + maxBn for the margin ----
    float mymax = 0.f;
#pragma unroll
    for (int i = 0; i < 4; ++i) {
        int code = t + i * 256;
        float nn = norm64v((const float4*)(emb + (size_t)code * 64));
        Bn_s[code] = nn;
        mymax = fmaxf(mymax, nn);
    }
#pragma unroll
    for (int m = 1; m < 64; m <<= 1) mymax = fmaxf(mymax, __shfl_xor(mymax, m, 64));
    if (lane == 0) wmax[wv] = mymax;
    if (blockIdx.x == 0) {
        ((uint4*)counts)[t] = make_uint4(0u, 0u, 0u, 0u);   // finish runs after D
    }
    __syncthreads();
    const float maxBn = fmaxf(fmaxf(wmax[0], wmax[1]), fmaxf(wmax[2], wmax[3]));
    if (blockIdx.x == 0) {
#pragma unroll
        for (int i = 0; i < 4; ++i) Bn_g[t + i * 256] = Bn_s[t + i * 256];
    }

    // ---- B-fragments: this lane's row (n = col = lane&31 in C/D layout),
    //      k-map: d = s*16 + g*8 + e (same map used for A below) ----
    bf16x8 bfrag[4];
    float xsq = 0.f;
    const float* zb = z_e + (size_t)b * 65536 + hw;
#pragma unroll
    for (int s = 0; s < 4; ++s) {
        bf16x8 f;
#pragma unroll
        for (int e = 0; e < 8; ++e) {
            int d = s * 16 + g * 8 + e;
            float x = zb[(size_t)d * 1024];
            xsq = __builtin_fmaf(x, x, xsq);
            f[e] = (short)f2bf(x);
        }
        bfrag[s] = f;
    }
    xsq += __shfl_xor(xsq, 32, 64);             // partner half holds other 32 d's
    const float margin = 0.017f * sqrtf(xsq * maxBn) + 1.0e-4f;

    // per-lane A-frag sub-offsets (code&7 == lane&7 since tiles are 32-aligned)
    const int swz = (lane & 7) << 4;
    const int offs[4] = { (0 * 32 + g * 16) ^ swz, (1 * 32 + g * 16) ^ swz,
                          (2 * 32 + g * 16) ^ swz, (3 * 32 + g * 16) ^ swz };
    const char* ebase = (const char*)ebf + (lane & 31) * 128;

    auto tile_acc = [&](int c) -> f32x16 {
        const char* p = ebase + c * 4096;
        bf16x8 a0 = *(const bf16x8*)(p + offs[0]);
        bf16x8 a1 = *(const bf16x8*)(p + offs[1]);
        bf16x8 a2 = *(const bf16x8*)(p + offs[2]);
        bf16x8 a3 = *(const bf16x8*)(p + offs[3]);
        f32x16 acc = {};
        acc = __builtin_amdgcn_mfma_f32_32x32x16_bf16(a0, bfrag[0], acc, 0, 0, 0);
        acc = __builtin_amdgcn_mfma_f32_32x32x16_bf16(a1, bfrag[1], acc, 0, 0, 0);
        acc = __builtin_amdgcn_mfma_f32_32x32x16_bf16(a2, bfrag[2], acc, 0, 0, 0);
        acc = __builtin_amdgcn_mfma_f32_32x32x16_bf16(a3, bfrag[3], acc, 0, 0, 0);
        return acc;
    };

    float4* encz = (float4*)(out + OUT_ENC) + (size_t)blockIdx.x * 32768;
    const float4 zero4 = make_float4(0.f, 0.f, 0.f, 0.f);

    // ---- pass 1: row min of s_hat (2 enc-fill stores per tile ride along) ----
    float runmin = 3.4e38f;
#pragma unroll 1
    for (int c = 0; c < 32; ++c) {
        f32x16 acc = tile_acc(c);
        encz[(size_t)(c * 2 + 0) * 256 + t] = zero4;
        encz[(size_t)(c * 2 + 1) * 256 + t] = zero4;
        float tm = 3.4e38f;
#pragma unroll
        for (int r = 0; r < 16; ++r) {
            int code = c * 32 + (r & 3) + 8 * (r >> 2) + 4 * g;
            float sv = __builtin_fmaf(-2.f, acc[r], Bn_s[code]);
            tm = fminf(tm, sv);
        }
        runmin = fminf(runmin, tm);
    }
    runmin = fminf(runmin, __shfl_xor(runmin, 32, 64));   // merge lane pair (same row)
    const float thr = runmin + margin;

    // ---- pass 2: collect candidates (<=3 per lane; overflow flagged) ----
    uint32_t cnt = 0, cc0 = 0, cc1 = 0, cc2 = 0;
#pragma unroll 1
    for (int c = 0; c < 32; ++c) {
        f32x16 acc = tile_acc(c);
        encz[(size_t)(64 + c * 2 + 0) * 256 + t] = zero4;
        encz[(size_t)(64 + c * 2 + 1) * 256 + t] = zero4;
#pragma unroll
        for (int r = 0; r < 16; ++r) {
            int code = c * 32 + (r & 3) + 8 * (r >> 2) + 4 * g;
            float sv = __builtin_fmaf(-2.f, acc[r], Bn_s[code]);
            if (sv <= thr) {
                if (cnt == 0) cc0 = (uint32_t)code;
                else if (cnt == 1) cc1 = (uint32_t)code;
                else if (cnt == 2) cc2 = (uint32_t)code;
                ++cnt;
            }
        }
    }
    // merge with partner lane (lane^32: other code-subset of the same row)
    uint32_t pcnt = __shfl_xor(cnt, 32, 64);
    uint32_t p0 = __shfl_xor(cc0, 32, 64);
    uint32_t p1 = __shfl_xor(cc1, 32, 64);
    uint32_t p2 = __shfl_xor(cc2, 32, 64);
    if (lane < 32) {
        uint32_t tot = cnt + pcnt;
        uint32_t info;
        if (cnt > 3u || pcnt > 3u || tot > 3u) {
            info = 3u << 30;                    // overflow -> full exact rescan
        } else {
            uint32_t ownm = (cnt >= 3u) ? 0x3FFFFFFFu : ((1u << (cnt * 10)) - 1u);
            uint32_t prtm = (pcnt >= 3u) ? 0x3FFFFFFFu : ((1u << (pcnt * 10)) - 1u);
            uint32_t ownp = (cc0 | (cc1 << 10) | (cc2 << 20)) & ownm;
            uint32_t prtp = (p0 | (p1 << 10) | (p2 << 20)) & prtm;
            info = ((tot - 1u) << 30) | ownp | (prtp << (cnt * 10));
        }
        rowinfo[n0 + wv * 32 + lane] = info;
    }
}

// ---------------------------------------------------------------------------
// finish kernel: 512 blocks x 256 thr, 64 rows/block.
// Resolves candidates bit-exactly (same fl(fl(A+B)-2C), same sequential
// 64-FMA chain, same norm64v as the old exact kernel — absmax 0.0 preserved),
// then z_st + one-hot ones + counts + fp64 loss partial (all as R5, with z
// kept in registers and also staged to LDS for the recheck chains).
// ---------------------------------------------------------------------------
__global__ __launch_bounds__(256)
void finish_kernel(const float* __restrict__ z_e, const float* __restrict__ emb,
                   const uint32_t* __restrict__ rowinfo,
                   const float* __restrict__ Bn_g,
                   uint32_t* __restrict__ counts, double* __restrict__ lp,
                   float* __restrict__ out) {
    __shared__ float zs[64 * 68];               // staged rows, stride 68
    __shared__ uint32_t scode[64];
    __shared__ unsigned long long pkey[64][3];
    __shared__ uint32_t pairbuf[192];
    __shared__ unsigned long long rbuf[4];
    __shared__ double lred[4];
    __shared__ uint32_t npairs, novf, ovfrow[8];
    const int t = threadIdx.x;
    const int n0 = blockIdx.x * 64;
    const int b = n0 >> 10, hw0 = n0 & 1023;
    if (t == 0) { npairs = 0u; novf = 0u; }
    const int hwi = t & 63, dg = t >> 6;

    // load z (coalesced 256B/wave-instr), keep in regs, stage to LDS
    float zreg[16];
    const size_t base = (size_t)b * 65536 + (size_t)(dg * 16) * 1024 + hw0 + hwi;
#pragma unroll
    for (int k = 0; k < 16; ++k) zreg[k] = z_e[base + (size_t)k * 1024];
#pragma unroll
    for (int m = 0; m < 4; ++m) {
        float4 v = make_float4(zreg[4 * m], zreg[4 * m + 1], zreg[4 * m + 2], zreg[4 * m + 3]);
        *(float4*)&zs[hwi * 68 + dg * 16 + 4 * m] = v;
    }
    __syncthreads();

    // decode rowinfo; enqueue rechecks
    if (t < 64) {
        uint32_t info = rowinfo[n0 + t];
        uint32_t c = (info >> 30) + 1u;
        if (c == 1u) {
            scode[t] = info & 1023u;
        } else if (c <= 3u) {
            uint32_t bs = atomicAdd(&npairs, c);
#pragma unroll
            for (uint32_t i = 0; i < 3; ++i)
                if (i < c)
                    pairbuf[bs + i] = ((uint32_t)t << 16) | (i << 12) | ((info >> (10u * i)) & 1023u);
        } else {
            uint32_t o = atomicAdd(&novf, 1u);
            if (o < 8u) ovfrow[o] = (uint32_t)t;
        }
    }
    __syncthreads();

    // candidate recheck: one (row,code) pair per thread, bit-exact chain
    if (t < (int)npairs) {
        uint32_t p = pairbuf[t];
        int row = (int)(p >> 16), slot = (int)((p >> 12) & 3u), code = (int)(p & 1023u);
        const float* xr = &zs[row * 68];
        const float* er = emb + (size_t)code * 64;
        float c = 0.f;
#pragma unroll
        for (int d = 0; d < 64; ++d) c = __builtin_fmaf(xr[d], er[d], c);
        float A = norm64v((const float4*)xr);
        float s = A + Bn_g[code];
        float dist = __builtin_fmaf(-2.f, c, s);      // single rounding == fl(s-2c)
        pkey[row][slot] = ((unsigned long long)fsort(dist) << 32) | (unsigned)code;
    }
    __syncthreads();

    // overflow rows (rare): full 1024-code exact rescan, block-wide
    {
        uint32_t no = novf < 8u ? novf : 8u;
        for (uint32_t o = 0; o < no; ++o) {
            int row = (int)ovfrow[o];
            const float* xr = &zs[row * 68];
            float A = norm64v((const float4*)xr);
            unsigned long long best = ~0ULL;
#pragma unroll 1
            for (int cc = 0; cc < 4; ++cc) {
                int code = t + cc * 256;
                const float* er = emb + (size_t)code * 64;
                float c = 0.f;
#pragma unroll
                for (int d = 0; d < 64; ++d) c = __builtin_fmaf(xr[d], er[d], c);
                float s = A + Bn_g[code];
                float dist = __builtin_fmaf(-2.f, c, s);
                unsigned long long key = ((unsigned long long)fsort(dist) << 32) | (unsigned)code;
                best = (key < best) ? key : best;
            }
#pragma unroll
            for (int m = 1; m < 64; m <<= 1) {
                unsigned long long ok = __shfl_xor(best, m, 64);
                best = (ok < best) ? ok : best;
            }
            if ((t & 63) == 0) rbuf[t >> 6] = best;
            __syncthreads();
            if (t == 0) {
                unsigned long long bb = rbuf[0];
#pragma unroll
                for (int w = 1; w < 4; ++w) bb = (rbuf[w] < bb) ? rbuf[w] : bb;
                scode[row] = (uint32_t)bb;
            }
            __syncthreads();
        }
    }
    // 2-3 candidate rows: pick exact min key (ties -> lowest code, numpy)
    if (t < 64) {
        uint32_t info = rowinfo[n0 + t];
        uint32_t c = (info >> 30) + 1u;
        if (c >= 2u && c <= 3u) {
            unsigned long long bb = pkey[t][0];
            if (c > 1u && pkey[t][1] < bb) bb = pkey[t][1];
            if (c > 2u && pkey[t][2] < bb) bb = pkey[t][2];
            scode[t] = (uint32_t)bb;
        }
    }
    __syncthreads();

    if (t < 64) {
        uint32_t code = scode[t];
        atomicAdd(&counts[code], 1u);
        out[(size_t)OUT_ENC + (size_t)(n0 + t) * 1024 + code] = 1.0f;
    }

    // z_st + loss from registers (exact per-element math unchanged)
    {
        const uint32_t code = scode[hwi];
        const float4* er4 = (const float4*)(emb + (size_t)code * 64) + dg * 4;
        double ls = 0.0;
#pragma unroll
        for (int k4 = 0; k4 < 4; ++k4) {
            float4 e4 = er4[k4];
            float fe0 = e4.x, fe1 = e4.y, fe2 = e4.z, fe3 = e4.w;
            {
                float z = zreg[k4 * 4 + 0]; float tt = fe0 - z;
                out[base + (size_t)(k4 * 4 + 0) * 1024] = z + tt; ls += (double)tt * (double)tt;
            }
            {
                float z = zreg[k4 * 4 + 1]; float tt = fe1 - z;
                out[base + (size_t)(k4 * 4 + 1) * 1024] = z + tt; ls += (double)tt * (double)tt;
            }
            {
                float z = zreg[k4 * 4 + 2]; float tt = fe2 - z;
                out[base + (size_t)(k4 * 4 + 2) * 1024] = z + tt; ls += (double)tt * (double)tt;
            }
            {
                float z = zreg[k4 * 4 + 3]; float tt = fe3 - z;
                out[base + (size_t)(k4 * 4 + 3) * 1024] = z + tt; ls += (double)tt * (double)tt;
            }
        }
#pragma unroll
        for (int m = 32; m >= 1; m >>= 1) ls += __shfl_down(ls, m, 64);
        if ((t & 63) == 0) lred[t >> 6] = ls;
    }
    __syncthreads();
    if (t == 0) lp[blockIdx.x] = lred[0] + lred[1] + lred[2] + lred[3];
}

// ---------------------------------------------------------------------------
// scalar kernel: one block; sum 512 fp64 loss partials + counts entropy.
// ---------------------------------------------------------------------------
__global__ void scalar_kernel(const uint32_t* __restrict__ counts,
                              const double* __restrict__ lp,
                              float* __restrict__ out) {
    __shared__ double redl[4], redh[4];
    const int t = threadIdx.x;   // 256
    double ls = 0.0;
    for (int i = t; i < 512; i += 256) ls += lp[i];
    double h = 0.0;
    for (int i = t; i < Kk; i += 256) {
        double p = (double)counts[i] * (1.0 / 32768.0);
        h += p * log(p + 1e-10);
    }
#pragma unroll
    for (int m = 32; m >= 1; m >>= 1) { ls += __shfl_down(ls, m, 64); h += __shfl_down(h, m, 64); }
    if ((t & 63) == 0) { redl[t >> 6] = ls; redh[t >> 6] = h; }
    __syncthreads();
    if (t == 0) {
        double L = redl[0] + redl[1] + redl[2] + redl[3];
        double H = redh[0] + redh[1] + redh[2] + redh[3];
        out[OUT_PERP] = (float)exp(-H);
        float m32 = (float)(L * (1.0 / 2097152.0));
        out[OUT_LOSS] = m32 + 0.25f * m32;   // q + 0.25*e, q==e numerically
    }
}

extern "C" void kernel_launch(void* const* d_in, const int* in_sizes, int n_in,
                              void* d_out, int out_size, void* d_ws, size_t ws_size,
                              hipStream_t stream) {
    const float* z_e = (const float*)d_in[0];
    const float* emb = (const float*)d_in[1];
    float* out = (float*)d_out;
    char* ws = (char*)d_ws;

    uint32_t* counts  = (uint32_t*)(ws + WS_CNT);
    double*   lp      = (double*)(ws + WS_LP);
    float*    Bn_g    = (float*)(ws + WS_BN);
    uint32_t* rowinfo = (uint32_t*)(ws + WS_RI);

    // no memsets: counts zeroed by D block 0; rowinfo/Bn_g/lp fully written
    dist_mfma<<<256, 256, 0, stream>>>(z_e, emb, rowinfo, counts, Bn_g, out);
    finish_kernel<<<512, 256, 0, stream>>>(z_e, emb, rowinfo, Bn_g, counts, lp, out);
    scalar_kernel<<<1, 256, 0, stream>>>(counts, lp, out);
}

// Round 3
// 214.940 us; speedup vs baseline: 1.1852x; 1.1852x over previous
//
#include <hip/hip_runtime.h>
#include <stdint.h>
#include <math.h>

// Problem constants
constexpr int Kk  = 1024;

// d_out layout (floats)
constexpr int OUT0_N   = 32 * 64 * 1024;       // 2097152 (z_st, [B,D,H,W])
constexpr int OUT_LOSS = OUT0_N;               // 2097152
constexpr int OUT_PERP = OUT0_N + 1;           // 2097153
constexpr int OUT_ENC  = OUT0_N + 2;           // 2097154

// d_ws layout (bytes) — everything fully written each call (ws is poisoned):
//   [0      .. 4096)     counts u32[1024]        (zeroed by dist block 0)
//   [4096   .. 12288)    loss partials double[1024] (fully written by finish)
//   [12288  .. 2109440)  lockey u64[32768][8]    per-(row,codegroup) best key,
//                        PLAIN stores, fully written by dist — no memset, no
//                        atomics (R4 lesson: avoid contended atomics; R6
//                        lesson: never drop below ~2 waves/SIMD).
constexpr size_t WS_CNT = 0;
constexpr size_t WS_LP  = 4096;
constexpr size_t WS_KEY = 12288;

// ---------------------------------------------------------------------------
// numpy-bit-exact 64-elem squared-norm: tt[d]=fl(x*x), 8 stride-8 sequential
// accumulators, pairwise combine. Contraction OFF. p: 16B-aligned, contiguous.
// ---------------------------------------------------------------------------
__device__ __forceinline__ float norm64v(const float4* __restrict__ p) {
#pragma clang fp contract(off)
    float tt[64];
#pragma unroll
    for (int q = 0; q < 16; ++q) {
        float4 v = p[q];
        tt[4 * q + 0] = v.x * v.x;
        tt[4 * q + 1] = v.y * v.y;
        tt[4 * q + 2] = v.z * v.z;
        tt[4 * q + 3] = v.w * v.w;
    }
    float r[8];
#pragma unroll
    for (int j = 0; j < 8; ++j) r[j] = tt[j];
#pragma unroll
    for (int i = 8; i < 64; i += 8)
#pragma unroll
        for (int j = 0; j < 8; ++j) r[j] += tt[i + j];
    return ((r[0] + r[1]) + (r[2] + r[3])) + ((r[4] + r[5]) + (r[6] + r[7]));
}

__device__ __forceinline__ uint32_t fsort(float f) {
    uint32_t b = __float_as_uint(f);
    return (b & 0x80000000u) ? ~b : (b | 0x80000000u);
}

// ---------------------------------------------------------------------------
// dist kernel (R5 exact-fp32 structure, proven at the enc-store floor):
// 2048 blocks = 256 rowgroups x 8 codegroups; 256 thr (16x16); per-thread
// 8x8; both tiles in LDS (stride 68, conflict-free); unroll-1 K-loop.
// R7 changes:
//  - winner per (row, cg) written with a PLAIN u64 store to lockey (fully
//    written; kills the 0xFF memset dispatch and the atomicMin path)
//  - the 16 enc zero-fill float4 stores are issued 1-per-K-iteration so the
//    store queue drains evenly under the FMA loop (fire-and-forget; the 134MB
//    enc fill is this kernel's true floor and the GEMM hides beneath it)
// ---------------------------------------------------------------------------
__global__ __launch_bounds__(256, 2)
void dist_kernel(const float* __restrict__ z_e, const float* __restrict__ emb,
                 unsigned long long* __restrict__ lockey,
                 uint32_t* __restrict__ counts,
                 float* __restrict__ out) {
    __shared__ float xs[128 * 68];   // [row][d]
    __shared__ float es[128 * 68];   // [code][d]
    __shared__ float An_s[128];
    __shared__ float Bn_s[128];
    const int tid = threadIdx.x;
    const int rg = blockIdx.x >> 3, cg = blockIdx.x & 7;
    const int n0 = rg * 128;
    const int b = n0 >> 10, hw0 = n0 & 1023;
    const float* zb = z_e + (size_t)b * 65536 + hw0;

    // stage x-tile: 4 coalesced d-slices per float4 LDS write
    {
        int hwi = tid & 127;
        int d4g = tid >> 7;   // 0..1
#pragma unroll
        for (int it = 0; it < 8; ++it) {
            int dbase = (d4g + it * 2) * 4;
            float4 v;
            v.x = zb[(size_t)(dbase + 0) * 1024 + hwi];
            v.y = zb[(size_t)(dbase + 1) * 1024 + hwi];
            v.z = zb[(size_t)(dbase + 2) * 1024 + hwi];
            v.w = zb[(size_t)(dbase + 3) * 1024 + hwi];
            *(float4*)&xs[hwi * 68 + dbase] = v;
        }
    }
    // stage e-tile: contiguous 32KB, coalesced float4
    {
        const float4* ep = (const float4*)(emb + (size_t)cg * 128 * 64);
#pragma unroll
        for (int it = 0; it < 8; ++it) {
            int j = tid + it * 256;      // 0..2047
            float4 v = ep[j];
            int c = j >> 4, d4 = j & 15;
            *(float4*)&es[c * 68 + d4 * 4] = v;
        }
    }
    // counts zero (block 0 only): finish runs after dist (stream order)
    if (blockIdx.x == 0) {
        ((uint4*)counts)[tid] = make_uint4(0u, 0u, 0u, 0u);
    }
    __syncthreads();

    // in-block norms from the staged tiles (identical bits to global)
    if (tid < 128) {
        An_s[tid] = norm64v((const float4*)&xs[tid * 68]);
    } else {
        int c = tid - 128;
        Bn_s[c] = norm64v((const float4*)&es[c * 68]);
    }
    __syncthreads();

    const int tx = tid & 15, ty = tid >> 4;
    float acc[8][8];
#pragma unroll
    for (int i = 0; i < 8; ++i)
#pragma unroll
        for (int j = 0; j < 8; ++j) acc[i][j] = 0.0f;

    // enc zero-fill target for this block (65536B slice). float4 cast at
    // 8-mod-16 byte base: global_store_dwordx4 needs only dword alignment —
    // harness-verified in R4/R5.
    const float4 zero4 = make_float4(0.0f, 0.0f, 0.0f, 0.0f);
    float4* encz = (float4*)(out + OUT_ENC) + (size_t)blockIdx.x * 4096;

#pragma unroll 1
    for (int d4 = 0; d4 < 16; ++d4) {
        encz[d4 * 256 + tid] = zero4;    // 1 of 16 fire-and-forget slices
        float4 xv[8], ev[8];
#pragma unroll
        for (int i = 0; i < 8; ++i) xv[i] = *(const float4*)&xs[(ty + 16 * i) * 68 + d4 * 4];
#pragma unroll
        for (int j = 0; j < 8; ++j) ev[j] = *(const float4*)&es[(tx + 16 * j) * 68 + d4 * 4];
#pragma unroll
        for (int i = 0; i < 8; ++i)
#pragma unroll
            for (int j = 0; j < 8; ++j) {
                float a = acc[i][j];
                a = __builtin_fmaf(xv[i].x, ev[j].x, a);
                a = __builtin_fmaf(xv[i].y, ev[j].y, a);
                a = __builtin_fmaf(xv[i].z, ev[j].z, a);
                a = __builtin_fmaf(xv[i].w, ev[j].w, a);
                acc[i][j] = a;
            }
    }

    // epilogue: dist = fl(fl(A+B) - 2C); per-row min over this block's codes
    float Ar[8], Bc[8];
#pragma unroll
    for (int i = 0; i < 8; ++i) Ar[i] = An_s[ty + 16 * i];
#pragma unroll
    for (int j = 0; j < 8; ++j) Bc[j] = Bn_s[tx + 16 * j];

#pragma unroll
    for (int i = 0; i < 8; ++i) {
        unsigned long long best = ~0ULL;
#pragma unroll
        for (int j = 0; j < 8; ++j) {
            float s = Ar[i] + Bc[j];
            float dist = s - 2.0f * acc[i][j];
            unsigned long long key = ((unsigned long long)fsort(dist) << 32)
                                   | (unsigned)(cg * 128 + tx + 16 * j);
            best = (key < best) ? key : best;
        }
#pragma unroll
        for (int m = 1; m < 16; m <<= 1) {
            unsigned long long o = __shfl_xor(best, m, 64);
            best = (o < best) ? o : best;
        }
        if (tx == 0) lockey[(size_t)(n0 + ty + 16 * i) * 8 + cg] = best;
    }
}

// ---------------------------------------------------------------------------
// finish kernel (R7): 1024 blocks x 256 thr, 32 rows/block (4 blocks/CU —
// R5's 512-block version was latency-limited at ~8us vs ~3.5us traffic floor).
//  - t<32: serial exact min over the row's 8 lockey words (same keys/tie rule
//    as R5's atomicMin), counts atomic (1024-way spread), enc 1.0 scatter
//  - z_st + fp64 loss partial: thread (hwi=t&31, dg=t>>5) walks 8 d values;
//    z_e/out accesses 128B-contiguous per quarter-wave (coalesced); emb via
//    2x float4 from the L2-resident table.
// Exact per-element math unchanged: tt = fl(emb[c][d]-z); out = fl(z+tt).
// ---------------------------------------------------------------------------
__global__ __launch_bounds__(256)
void finish_kernel(const float* __restrict__ z_e,
                   const float* __restrict__ emb,
                   const unsigned long long* __restrict__ lockey,
                   uint32_t* __restrict__ counts,
                   double* __restrict__ lp,
                   float* __restrict__ out) {
    __shared__ uint32_t scode[32];
    __shared__ double lred[4];
    const int t = threadIdx.x;
    const int n0 = blockIdx.x * 32;                // rows n0..n0+31, same b
    const int b = n0 >> 10, hw0 = n0 & 1023;

    if (t < 32) {
        const unsigned long long* k8 = lockey + (size_t)(n0 + t) * 8;
        unsigned long long best = k8[0];
#pragma unroll
        for (int i = 1; i < 8; ++i) {
            unsigned long long k = k8[i];
            best = (k < best) ? k : best;
        }
        uint32_t code = (uint32_t)best;
        scode[t] = code;
        atomicAdd(&counts[code], 1u);
        // the single 1.0 of this row's one-hot (zeros laid down by dist)
        out[(size_t)OUT_ENC + (size_t)(n0 + t) * 1024 + code] = 1.0f;
    }
    __syncthreads();

    const int hwi = t & 31, dg = t >> 5;           // dg = 0..7
    const uint32_t code = scode[hwi];
    const float4* er4 = (const float4*)(emb + (size_t)code * 64) + dg * 2;
    const size_t base = (size_t)b * 65536 + (size_t)(dg * 8) * 1024 + hw0 + hwi;

    double ls = 0.0;
#pragma unroll
    for (int k4 = 0; k4 < 2; ++k4) {
        float4 e4 = er4[k4];
        float f0 = e4.x, f1 = e4.y, f2 = e4.z, f3 = e4.w;
        size_t off = base + (size_t)(k4 * 4) * 1024;
        {
            float z = z_e[off];            float tt = f0 - z;
            out[off] = z + tt;             ls += (double)tt * (double)tt;
        }
        {
            float z = z_e[off + 1024];     float tt = f1 - z;
            out[off + 1024] = z + tt;      ls += (double)tt * (double)tt;
        }
        {
            float z = z_e[off + 2048];     float tt = f2 - z;
            out[off + 2048] = z + tt;      ls += (double)tt * (double)tt;
        }
        {
            float z = z_e[off + 3072];     float tt = f3 - z;
            out[off + 3072] = z + tt;      ls += (double)tt * (double)tt;
        }
    }
#pragma unroll
    for (int m = 32; m >= 1; m >>= 1) ls += __shfl_down(ls, m, 64);
    if ((t & 63) == 0) lred[t >> 6] = ls;
    __syncthreads();
    if (t == 0) lp[blockIdx.x] = lred[0] + lred[1] + lred[2] + lred[3];
}

// ---------------------------------------------------------------------------
// scalar kernel: one block; sum 1024 fp64 loss partials + counts entropy.
// Stream ordering (kernel boundary) provides coherence — no fence needed.
// ---------------------------------------------------------------------------
__global__ void scalar_kernel(const uint32_t* __restrict__ counts,
                              const double* __restrict__ lp,
                              float* __restrict__ out) {
    __shared__ double redl[4], redh[4];
    const int t = threadIdx.x;   // 256
    double ls = 0.0;
    for (int i = t; i < 1024; i += 256) ls += lp[i];
    double h = 0.0;
    for (int i = t; i < Kk; i += 256) {
        double p = (double)counts[i] * (1.0 / 32768.0);
        h += p * log(p + 1e-10);
    }
#pragma unroll
    for (int m = 32; m >= 1; m >>= 1) { ls += __shfl_down(ls, m, 64); h += __shfl_down(h, m, 64); }
    if ((t & 63) == 0) { redl[t >> 6] = ls; redh[t >> 6] = h; }
    __syncthreads();
    if (t == 0) {
        double L = redl[0] + redl[1] + redl[2] + redl[3];
        double H = redh[0] + redh[1] + redh[2] + redh[3];
        out[OUT_PERP] = (float)exp(-H);
        float m32 = (float)(L * (1.0 / 2097152.0));
        out[OUT_LOSS] = m32 + 0.25f * m32;   // q + 0.25*e, q==e numerically
    }
}

extern "C" void kernel_launch(void* const* d_in, const int* in_sizes, int n_in,
                              void* d_out, int out_size, void* d_ws, size_t ws_size,
                              hipStream_t stream) {
    const float* z_e = (const float*)d_in[0];
    const float* emb = (const float*)d_in[1];
    float* out = (float*)d_out;
    char* ws = (char*)d_ws;

    uint32_t* counts = (uint32_t*)(ws + WS_CNT);
    double*   lp     = (double*)(ws + WS_LP);
    unsigned long long* lockey = (unsigned long long*)(ws + WS_KEY);

    // no memsets: counts zeroed by dist block 0; lockey/lp fully written
    dist_kernel<<<2048, 256, 0, stream>>>(z_e, emb, lockey, counts, out);
    finish_kernel<<<1024, 256, 0, stream>>>(z_e, emb, lockey, counts, lp, out);
    scalar_kernel<<<1, 256, 0, stream>>>(counts, lp, out);
}